// Round 6
// baseline (304.107 us; speedup 1.0000x reference)
//
#include <hip/hip_runtime.h>
#include <hip/hip_bf16.h>
#include <math.h>

// B=16, S=2048, D=1024, HD=64
constexpr int Bsz  = 16;
constexpr int Seq  = 2048;
constexpr int Din  = 1024;
constexpr int Hd   = 64;
constexpr int Rows = Bsz * Seq;   // 32768

typedef short  short8 __attribute__((ext_vector_type(8)));
typedef float  f32x4  __attribute__((ext_vector_type(4)));

__device__ __forceinline__ short bf16_bits(float f) {
    __hip_bfloat16 h = __float2bfloat16(f);   // RNE
    return __builtin_bit_cast(short, h);
}

// ---------------------------------------------------------------------------
// Wf fragment order: [chunk k/32][f = wg*4+nt][lane = quad*16+l16][j 0..8)
//   holds W_wg[k = chunk*32 + quad*8 + j][n = nt*16 + l16]
// ---------------------------------------------------------------------------
__global__ __launch_bounds__(256) void wt_prep(
    const float* __restrict__ Wq, const float* __restrict__ Wk,
    const float* __restrict__ Wv, short* __restrict__ Wf)
{
    const int u     = blockIdx.x * 256 + threadIdx.x;   // 0..24575
    const int chunk = u / 768;
    const int rem   = u - chunk * 768;
    const int f     = rem >> 6;
    const int lane  = rem & 63;
    const int wg    = f >> 2, nt = f & 3;
    const int quad  = lane >> 4, l16 = lane & 15;
    const float* W  = (wg == 0) ? Wq : (wg == 1) ? Wk : Wv;
    const int k0 = chunk * 32 + quad * 8;
    const int n  = nt * 16 + l16;
    short8 v;
    #pragma unroll
    for (int j = 0; j < 8; ++j) v[j] = bf16_bits(W[(size_t)(k0 + j) * Hd + n]);
    *(short8*)(Wf + (size_t)u * 8) = v;
}

// ---------------------------------------------------------------------------
// QKV v6: K-split x4 for occupancy.  grid 1024 x 512 (8 waves).
// Block = 32 rows.  wave = kh*2 + rg: rg = 16-row group, kh = k-quarter
// (8 chunks each).  Partial acc merged via 48 KB LDS tree; epilogue emits
// the same Qf/Kf/Vf fragment layouts as v5 (attn unchanged).
// ---------------------------------------------------------------------------
__global__ __launch_bounds__(512, 4) void qkv_kernel(
    const float* __restrict__ x,
    const short* __restrict__ Wf,
    const float* __restrict__ bq, const float* __restrict__ bk,
    const float* __restrict__ bv,
    short* __restrict__ Qf, short* __restrict__ Kf, short* __restrict__ Vf)
{
    const int tid  = threadIdx.x;
    const int wave = tid >> 6;        // 0..7
    const int lane = tid & 63;
    const int quad = lane >> 4;
    const int l16  = lane & 15;
    const int rg   = wave & 1;        // 16-row group within the 32-row block
    const int kh   = wave >> 1;       // k-quarter 0..3
    const int bx   = blockIdx.x;

    const float* xrow = x + (size_t)(bx * 32 + rg * 16 + l16) * Din + quad * 8;

    f32x4 acc[12] = {};

    const int c0 = kh * 8;
    #pragma unroll 2
    for (int c = c0; c < c0 + 8; ++c) {
        const float4 a0 = *(const float4*)(xrow + c * 32);
        const float4 a1 = *(const float4*)(xrow + c * 32 + 4);
        short8 af;
        af[0] = bf16_bits(a0.x); af[1] = bf16_bits(a0.y);
        af[2] = bf16_bits(a0.z); af[3] = bf16_bits(a0.w);
        af[4] = bf16_bits(a1.x); af[5] = bf16_bits(a1.y);
        af[6] = bf16_bits(a1.z); af[7] = bf16_bits(a1.w);
        const short* wsrc = Wf + (size_t)c * 6144 + lane * 8;
        #pragma unroll
        for (int f = 0; f < 12; ++f) {
            const short8 bb = *(const short8*)(wsrc + f * 512);
            acc[f] = __builtin_amdgcn_mfma_f32_16x16x32_bf16(af, bb, acc[f], 0, 0, 0);
        }
    }

    // ---- LDS merge tree:  kh0 += kh1;  kh2 += kh3;  then kh0 += kh2 ----
    __shared__ __align__(16) unsigned char smem[49152];
    float* M  = (float*)smem;                       // [2 slot][2 rg][12][64][4]
    short* eS = (short*)smem;                       // [2 rg][2 wg][16*72]
    short* eV = (short*)(smem + 2 * 2 * 1152 * 2);  // [64*40]

    if (kh == 1 || kh == 3) {
        const int slot = (kh == 1) ? 0 : 1;
        float* dst = M + (size_t)((slot * 2 + rg) * 12) * 256 + lane * 4;
        #pragma unroll
        for (int f = 0; f < 12; ++f) *(f32x4*)(dst + f * 256) = acc[f];
    }
    __syncthreads();
    if (kh == 0 || kh == 2) {
        const int slot = (kh == 0) ? 0 : 1;
        const float* src = M + (size_t)((slot * 2 + rg) * 12) * 256 + lane * 4;
        #pragma unroll
        for (int f = 0; f < 12; ++f) acc[f] += *(const f32x4*)(src + f * 256);
    }
    __syncthreads();
    if (kh == 2) {
        float* dst = M + (size_t)(rg * 12) * 256 + lane * 4;
        #pragma unroll
        for (int f = 0; f < 12; ++f) *(f32x4*)(dst + f * 256) = acc[f];
    }
    __syncthreads();
    if (kh == 0) {
        const float* src = M + (size_t)(rg * 12) * 256 + lane * 4;
        #pragma unroll
        for (int f = 0; f < 12; ++f) acc[f] += *(const f32x4*)(src + f * 256);
    }
    __syncthreads();   // M reads done; eS/eV (aliased) may now be written

    // ---- epilogue (kh==0 waves only; layouts identical to v5) ----
    if (kh == 0) {
        // Q (wg=0) and K (wg=1): C-layout -> A/B-layout via per-rg strip
        #pragma unroll
        for (int wg = 0; wg < 2; ++wg) {
            const float* bias = wg ? bk : bq;
            short* strip = eS + (size_t)(rg * 2 + wg) * 1152;
            #pragma unroll
            for (int nt = 0; nt < 4; ++nt) {
                const float bb = bias[nt * 16 + l16];
                #pragma unroll
                for (int r = 0; r < 4; ++r)
                    strip[(quad * 4 + r) * 72 + nt * 16 + l16] =
                        bf16_bits(acc[wg * 4 + nt][r] + bb);
            }
        }
        #pragma unroll
        for (int wg = 0; wg < 2; ++wg) {
            const short* strip = eS + (size_t)(rg * 2 + wg) * 1152;
            const short8 v0 = *(const short8*)&strip[l16 * 72 + quad * 8];
            const short8 v1 = *(const short8*)&strip[l16 * 72 + 32 + quad * 8];
            if (wg == 0) {
                const size_t tg = (size_t)bx * 2 + rg;   // global 16-row group
                *(short8*)(Qf + (tg * 2 + 0) * 512 + lane * 8) = v0;
                *(short8*)(Qf + (tg * 2 + 1) * 512 + lane * 8) = v1;
            } else {
                const size_t t64 = bx >> 1;              // 64-row tile
                const int ntK = (bx & 1) * 2 + rg;       // 16-row slot in tile
                *(short8*)(Kf + ((t64 * 2 + 0) * 4 + ntK) * 512 + lane * 8) = v0;
                *(short8*)(Kf + ((t64 * 2 + 1) * 4 + ntK) * 512 + lane * 8) = v1;
            }
        }
        // V: [d][local token] strip for this 32-row block
        #pragma unroll
        for (int nt = 0; nt < 4; ++nt) {
            const float bb = bv[nt * 16 + l16];
            #pragma unroll
            for (int r = 0; r < 4; ++r)
                eV[(nt * 16 + l16) * 40 + rg * 16 + quad * 4 + r] =
                    bf16_bits(acc[8 + nt][r] + bb);
        }
    }
    __syncthreads();   // eV ready
    if (tid < 256) {
        const int lane_s = tid & 63;
        const int ntd    = tid >> 6;             // 0..3  (d group)
        const int q_s    = lane_s >> 4, l_s = lane_s & 15;
        const size_t t64 = bx >> 1;
        const int th     = bx & 1;               // 32-token half of the tile
        const short8 v = *(const short8*)&eV[(ntd * 16 + l_s) * 40 + q_s * 8];
        *(short8*)(Vf + ((t64 * 2 + th) * 4 + ntd) * 512 + lane_s * 8) = v;
    }
}

// ---------------------------------------------------------------------------
// Flash attention v5 (unchanged): split-kt across 4 waves of one 16-row q
// strip + LDS merge.  grid (128, 16) x 256.
// ---------------------------------------------------------------------------
__global__ __launch_bounds__(256) void attn_kernel(
    const short* __restrict__ Qf, const short* __restrict__ Kf,
    const short* __restrict__ Vf, float* __restrict__ out)
{
    const int tid  = threadIdx.x;
    const int wave = tid >> 6;
    const int lane = tid & 63;
    const int quad = lane >> 4;
    const int l16  = lane & 15;
    const int b    = blockIdx.y;
    const int bx   = blockIdx.x;
    const int qs   = (bx & 1) ? (127 - (bx >> 1)) : (bx >> 1);  // balance remap
    const int dTile = qs >> 2;
    const int tiles = dTile + 1;
    const int qoff  = (qs & 3) * 16;

    __shared__ __align__(16) unsigned char sm[17408 + 512];
    short* Ps   = (short*)sm;              // [4][16*72] per-wave strips (loop)
    float* Obuf = (float*)sm;              // [4][16][68]  (merge; aliases Ps)
    float* mb   = (float*)(sm + 17408);    // [4][16]
    float* lb   = mb + 64;                 // [4][16]

    const size_t tg = (size_t)b * 128 + qs;
    const short8 qf0 = *(const short8*)(Qf + (tg * 2 + 0) * 512 + lane * 8);
    const short8 qf1 = *(const short8*)(Qf + (tg * 2 + 1) * 512 + lane * 8);

    f32x4 o[4] = {};
    float m_run[4], l_run[4];
    #pragma unroll
    for (int r = 0; r < 4; ++r) { m_run[r] = -INFINITY; l_run[r] = 0.0f; }

    const float C = 0.125f * 1.44269504088896340736f;  // scale * log2(e)

    for (int kt = wave; kt < tiles; kt += 4) {
        const short* ktile = Kf + (size_t)(b * 32 + kt) * 4096;
        const short* vtile = Vf + (size_t)(b * 32 + kt) * 4096;

        f32x4 s[4] = {};
        #pragma unroll
        for (int nt = 0; nt < 4; ++nt) {
            const short8 kf0 = *(const short8*)(ktile + ((0 * 4 + nt) * 64 + lane) * 8);
            const short8 kf1 = *(const short8*)(ktile + ((1 * 4 + nt) * 64 + lane) * 8);
            s[nt] = __builtin_amdgcn_mfma_f32_16x16x32_bf16(qf0, kf0, s[nt], 0, 0, 0);
            s[nt] = __builtin_amdgcn_mfma_f32_16x16x32_bf16(qf1, kf1, s[nt], 0, 0, 0);
        }

        if (kt == dTile) {
            #pragma unroll
            for (int nt = 0; nt < 4; ++nt) {
                const int kg = nt * 16 + l16;
                #pragma unroll
                for (int r = 0; r < 4; ++r) {
                    const int qg = qoff + quad * 4 + r;
                    s[nt][r] = (kg <= qg) ? s[nt][r] * C : -INFINITY;
                }
            }
        } else {
            #pragma unroll
            for (int nt = 0; nt < 4; ++nt)
                #pragma unroll
                for (int r = 0; r < 4; ++r) s[nt][r] *= C;
        }

        float rm[4];
        #pragma unroll
        for (int r = 0; r < 4; ++r)
            rm[r] = fmaxf(fmaxf(s[0][r], s[1][r]), fmaxf(s[2][r], s[3][r]));
        #pragma unroll
        for (int off = 1; off < 16; off <<= 1)
            #pragma unroll
            for (int r = 0; r < 4; ++r)
                rm[r] = fmaxf(rm[r], __shfl_xor(rm[r], off));

        float alpha[4];
        #pragma unroll
        for (int r = 0; r < 4; ++r) {
            const float mn = fmaxf(m_run[r], rm[r]);
            alpha[r] = exp2f(m_run[r] - mn);
            m_run[r] = mn;
        }

        float rs[4] = {0.f, 0.f, 0.f, 0.f};
        #pragma unroll
        for (int nt = 0; nt < 4; ++nt)
            #pragma unroll
            for (int r = 0; r < 4; ++r) {
                const float p = exp2f(s[nt][r] - m_run[r]);
                s[nt][r] = p;
                rs[r] += p;
            }
        #pragma unroll
        for (int off = 1; off < 16; off <<= 1)
            #pragma unroll
            for (int r = 0; r < 4; ++r)
                rs[r] += __shfl_xor(rs[r], off);
        #pragma unroll
        for (int r = 0; r < 4; ++r) l_run[r] = l_run[r] * alpha[r] + rs[r];

        #pragma unroll
        for (int r = 0; r < 4; ++r) {
            o[0][r] *= alpha[r]; o[1][r] *= alpha[r];
            o[2][r] *= alpha[r]; o[3][r] *= alpha[r];
        }

        #pragma unroll
        for (int nt = 0; nt < 4; ++nt)
            #pragma unroll
            for (int r = 0; r < 4; ++r)
                Ps[wave * 1152 + (quad * 4 + r) * 72 + nt * 16 + l16] = bf16_bits(s[nt][r]);

        const short8 pf0 = *(const short8*)&Ps[wave * 1152 + l16 * 72 + quad * 8];
        const short8 pf1 = *(const short8*)&Ps[wave * 1152 + l16 * 72 + 32 + quad * 8];

        #pragma unroll
        for (int nt = 0; nt < 4; ++nt) {
            const short8 vA = *(const short8*)(vtile + ((0 * 4 + nt) * 64 + lane) * 8);
            const short8 vB = *(const short8*)(vtile + ((1 * 4 + nt) * 64 + lane) * 8);
            o[nt] = __builtin_amdgcn_mfma_f32_16x16x32_bf16(pf0, vA, o[nt], 0, 0, 0);
            o[nt] = __builtin_amdgcn_mfma_f32_16x16x32_bf16(pf1, vB, o[nt], 0, 0, 0);
        }
    }

    // ---- 4-wave merge ----
    if (l16 == 0) {
        #pragma unroll
        for (int r = 0; r < 4; ++r) mb[wave * 16 + quad * 4 + r] = m_run[r];
    }
    __syncthreads();

    float fac[4];
    #pragma unroll
    for (int r = 0; r < 4; ++r) {
        const int row = quad * 4 + r;
        const float mg = fmaxf(fmaxf(mb[row], mb[16 + row]),
                               fmaxf(mb[32 + row], mb[48 + row]));
        fac[r] = exp2f(m_run[r] - mg);
    }
    if (l16 == 0) {
        #pragma unroll
        for (int r = 0; r < 4; ++r) lb[wave * 16 + quad * 4 + r] = l_run[r] * fac[r];
    }
    #pragma unroll
    for (int nt = 0; nt < 4; ++nt)
        #pragma unroll
        for (int r = 0; r < 4; ++r)
            Obuf[wave * 1088 + (quad * 4 + r) * 68 + nt * 16 + l16] = o[nt][r] * fac[r];
    __syncthreads();

    {
        const int row = tid >> 4;
        const int c0  = (tid & 15) * 4;
        const float lsum = lb[row] + lb[16 + row] + lb[32 + row] + lb[48 + row];
        float4 a = *(const float4*)&Obuf[0 * 1088 + row * 68 + c0];
        const float4 a1 = *(const float4*)&Obuf[1 * 1088 + row * 68 + c0];
        const float4 a2 = *(const float4*)&Obuf[2 * 1088 + row * 68 + c0];
        const float4 a3 = *(const float4*)&Obuf[3 * 1088 + row * 68 + c0];
        a.x += a1.x + a2.x + a3.x;  a.y += a1.y + a2.y + a3.y;
        a.z += a1.z + a2.z + a3.z;  a.w += a1.w + a2.w + a3.w;
        const float inv = 1.0f / lsum;
        float4 r4 = make_float4(a.x * inv, a.y * inv, a.z * inv, a.w * inv);
        *(float4*)(out + ((size_t)b * Seq + qs * 16 + row) * Hd + c0) = r4;
    }
}

// ---------------------------------------------------------------------------
extern "C" void kernel_launch(void* const* d_in, const int* in_sizes, int n_in,
                              void* d_out, int out_size, void* d_ws, size_t ws_size,
                              hipStream_t stream)
{
    const float* x  = (const float*)d_in[0];
    const float* Wq = (const float*)d_in[1];
    const float* bq = (const float*)d_in[2];
    const float* Wk = (const float*)d_in[3];
    const float* bk = (const float*)d_in[4];
    const float* Wv = (const float*)d_in[5];
    const float* bv = (const float*)d_in[6];
    float* out = (float*)d_out;

    short* Qf = (short*)d_ws;                    // 4 MB
    short* Kf = Qf + (size_t)Rows * Hd;          // 4 MB
    short* Vf = Kf + (size_t)Rows * Hd;          // 4 MB
    short* Wf = Vf + (size_t)Rows * Hd;          // 384 KB

    wt_prep<<<96, 256, 0, stream>>>(Wq, Wk, Wv, Wf);
    qkv_kernel<<<1024, 512, 0, stream>>>(x, Wf, bq, bk, bv, Qf, Kf, Vf);
    attn_kernel<<<dim3(128, 16), 256, 0, stream>>>(Qf, Kf, Vf, out);
}